// Round 1
// baseline (17121.706 us; speedup 1.0000x reference)
//
#include <hip/hip_runtime.h>
#include <math.h>

#define HD 128
#define NN 512
#define BBATCH 4

__device__ __forceinline__ float silu_f(float v) { return v / (1.f + __expf(-v)); }

// ---------------- time MLP: t -> t_emb (B,128) ----------------
__global__ void k_time(const float* __restrict__ t,
                       const float* __restrict__ w1, const float* __restrict__ b1,
                       const float* __restrict__ w2, const float* __restrict__ b2,
                       float* __restrict__ t_emb) {
    int b = blockIdx.x;
    int h = threadIdx.x;           // 0..127
    __shared__ float te[64];
    __shared__ float hid[128];
    float tv = t[b];
    if (h < 32) {
        const float cst = (float)(-2.302585092994046 * 4.0 / 31.0); // -ln(10000)/31
        float freq = __expf((float)h * cst);
        float ang = tv * freq;
        te[h]      = sinf(ang);
        te[h + 32] = cosf(ang);
    }
    __syncthreads();
    float acc = b1[h];
    #pragma unroll 8
    for (int k = 0; k < 64; ++k) acc += te[k] * w1[k * HD + h];
    hid[h] = silu_f(acc);
    __syncthreads();
    float acc2 = b2[h];
    #pragma unroll 8
    for (int k = 0; k < HD; ++k) acc2 += hid[k] * w2[k * HD + h];
    t_emb[b * HD + h] = acc2;
}

// ---------------- broadcast t_emb -> h (B,N,H) ----------------
__global__ void k_bcast(const float* __restrict__ t_emb, float* __restrict__ h) {
    int idx = blockIdx.x * 256 + threadIdx.x;   // B*N*H = 262144
    int hch = idx & 127;
    int b = idx >> 16;                           // N*H = 65536
    h[idx] = t_emb[b * HD + hch];
}

// ---------------- per-node projections A = h@W1_top + b1, Bp = h@W1_mid ----------------
__global__ void k_proj(const float* __restrict__ h,
                       const float* __restrict__ w1,   // (272,128) of this layer
                       const float* __restrict__ b1,
                       float* __restrict__ A, float* __restrict__ Bp) {
    int node = blockIdx.x;       // b*N+i, 2048 total
    int hc = threadIdx.x;        // 0..127
    __shared__ float hrow[HD];
    hrow[hc] = h[node * HD + hc];
    __syncthreads();
    float a = b1[hc];
    float bb = 0.f;
    #pragma unroll 8
    for (int k = 0; k < HD; ++k) {
        a  += hrow[k] * w1[k * HD + hc];
        bb += hrow[k] * w1[(HD + k) * HD + hc];
    }
    A[node * HD + hc]  = a;
    Bp[node * HD + hc] = bb;
}

// ---------------- the big edge kernel ----------------
// block = 256 threads = 2 groups x 128 channels; each group does 4 j's at once.
// LDS: W2^T and cw1^T (pad 132), rbf weights^T (pad 17), biases, activations.
__global__ __launch_bounds__(256, 1)
void k_edge(const float* __restrict__ x, const float* __restrict__ h_in,
            float* __restrict__ h_out,
            const float* __restrict__ A, const float* __restrict__ Bp,
            const float* __restrict__ w1r,   // (16,128) rbf rows of msg_w1[l]
            const float* __restrict__ w2,    // (128,128)
            const float* __restrict__ b2,
            const float* __restrict__ cw1,   // (128,128)
            const float* __restrict__ cb1,
            const float* __restrict__ cw2,   // (128)
            const float* __restrict__ cb2,   // (1)
            float* __restrict__ out) {
    extern __shared__ float sm[];
    float* sW2T = sm;                       // 128*132
    float* sC1T = sW2T + 128 * 132;         // 128*132
    float* sW1r = sC1T + 128 * 132;         // 128*17
    float* sB2  = sW1r + 128 * 17;          // 128
    float* sCB1 = sB2 + 128;                // 128
    float* sCW2 = sCB1 + 128;               // 128
    float* sMA  = sCW2 + 128;               // 8*128
    float* sMM  = sMA + 8 * 128;            // 8*128
    float* sRBF = sMM + 8 * 128;            // 2*4*16
    float* sRED = sRBF + 128;               // 16
    float* sHP  = sRED + 16;                // 128
    float* sCA  = sHP + 128;                // 8

    const int tid = threadIdx.x;
    const int c = tid & 127;                // channel
    const int g = tid >> 7;                 // group 0/1
    const int node = blockIdx.x;            // b*N + i
    const int b = node >> 9;

    // preload weights (coalesced global reads, transposed LDS writes)
    for (int idx = tid; idx < 128 * 128; idx += 256) {
        int k = idx >> 7, hh = idx & 127;
        sW2T[hh * 132 + k] = w2[idx];
        sC1T[hh * 132 + k] = cw1[idx];
    }
    for (int idx = tid; idx < 16 * 128; idx += 256) {
        int r = idx >> 7, hh = idx & 127;
        sW1r[hh * 17 + r] = w1r[idx];
    }
    if (tid < 128) { sB2[tid] = b2[tid]; sCB1[tid] = cb1[tid]; sCW2[tid] = cw2[tid]; }

    const float xi0 = x[node * 3 + 0], xi1 = x[node * 3 + 1], xi2 = x[node * 3 + 2];
    const float aI = A[node * HD + c];
    const float cb2v = cb2[0];
    float hreg = 0.f;
    float ca0 = 0.f, ca1 = 0.f, ca2 = 0.f;
    __syncthreads();

    const float cstep = 10.f / 15.f;        // RBF center spacing
    const float rbf_k = 1.28f;              // 1/(2*width^2), width=0.625

    for (int it = 0; it < NN / 8; ++it) {
        const int jb = it * 8 + g * 4;
        float dist[4], mask[4], dx[4], dy[4], dz[4];
        #pragma unroll
        for (int jv = 0; jv < 4; ++jv) {
            int j = jb + jv;
            const float* xj = &x[(b * NN + j) * 3];
            float d0 = xj[0] - xi0, d1 = xj[1] - xi1, d2 = xj[2] - xi2;
            float d2s = d0 * d0 + d1 * d1 + d2 * d2;
            float d = sqrtf(d2s);
            dist[jv] = d;
            mask[jv] = (d < 10.f && d > 0.f) ? 1.f : 0.f;
            float inv = 1.f / (d + 1e-8f);
            dx[jv] = d0 * inv; dy[jv] = d1 * inv; dz[jv] = d2 * inv;
        }
        if (c < 64) {                        // cooperative RBF: 4 jv x 16 r per group
            int jv = c >> 4, r = c & 15;
            float dd = dist[jv] - (float)r * cstep;
            sRBF[g * 64 + jv * 16 + r] = __expf(-dd * dd * rbf_k);
        }
        __syncthreads();                     // B1: RBF ready

        // pre-activation + silu -> sMA
        #pragma unroll
        for (int jv = 0; jv < 4; ++jv) {
            int j = jb + jv;
            float pre = aI + Bp[(b * NN + j) * HD + c];
            #pragma unroll
            for (int r = 0; r < 16; ++r)
                pre += sRBF[g * 64 + jv * 16 + r] * sW1r[c * 17 + r];
            sMA[(g * 4 + jv) * HD + c] = silu_f(pre);
        }
        __syncthreads();                     // B2: MA ready

        // msg = MA @ W2 + b2 (4 edges at once, weights reused)
        {
            float acc0 = sB2[c], acc1 = sB2[c], acc2 = sB2[c], acc3 = sB2[c];
            const float* wrow = &sW2T[c * 132];
            const float* m0 = &sMA[(g * 4 + 0) * HD];
            const float* m1 = &sMA[(g * 4 + 1) * HD];
            const float* m2 = &sMA[(g * 4 + 2) * HD];
            const float* m3 = &sMA[(g * 4 + 3) * HD];
            #pragma unroll 8
            for (int k4 = 0; k4 < 32; ++k4) {
                float4 w = *(const float4*)&wrow[k4 * 4];
                float4 a0 = *(const float4*)&m0[k4 * 4];
                float4 a1 = *(const float4*)&m1[k4 * 4];
                float4 a2 = *(const float4*)&m2[k4 * 4];
                float4 a3 = *(const float4*)&m3[k4 * 4];
                acc0 += w.x * a0.x + w.y * a0.y + w.z * a0.z + w.w * a0.w;
                acc1 += w.x * a1.x + w.y * a1.y + w.z * a1.z + w.w * a1.w;
                acc2 += w.x * a2.x + w.y * a2.y + w.z * a2.z + w.w * a2.w;
                acc3 += w.x * a3.x + w.y * a3.y + w.z * a3.z + w.w * a3.w;
            }
            float msg0 = acc0 * mask[0];
            float msg1 = acc1 * mask[1];
            float msg2 = acc2 * mask[2];
            float msg3 = acc3 * mask[3];
            sMM[(g * 4 + 0) * HD + c] = msg0;
            sMM[(g * 4 + 1) * HD + c] = msg1;
            sMM[(g * 4 + 2) * HD + c] = msg2;
            sMM[(g * 4 + 3) * HD + c] = msg3;
            hreg += msg0 + msg1 + msg2 + msg3;
        }
        __syncthreads();                     // B3: MM ready

        // c_hidden = silu(MM @ cw1 + cb1); contrib = c_hidden * cw2; reduce over channels
        {
            float e0 = sCB1[c], e1 = sCB1[c], e2 = sCB1[c], e3 = sCB1[c];
            const float* crow = &sC1T[c * 132];
            const float* q0 = &sMM[(g * 4 + 0) * HD];
            const float* q1 = &sMM[(g * 4 + 1) * HD];
            const float* q2 = &sMM[(g * 4 + 2) * HD];
            const float* q3 = &sMM[(g * 4 + 3) * HD];
            #pragma unroll 8
            for (int k4 = 0; k4 < 32; ++k4) {
                float4 w = *(const float4*)&crow[k4 * 4];
                float4 a0 = *(const float4*)&q0[k4 * 4];
                float4 a1 = *(const float4*)&q1[k4 * 4];
                float4 a2 = *(const float4*)&q2[k4 * 4];
                float4 a3 = *(const float4*)&q3[k4 * 4];
                e0 += w.x * a0.x + w.y * a0.y + w.z * a0.z + w.w * a0.w;
                e1 += w.x * a1.x + w.y * a1.y + w.z * a1.z + w.w * a1.w;
                e2 += w.x * a2.x + w.y * a2.y + w.z * a2.z + w.w * a2.w;
                e3 += w.x * a3.x + w.y * a3.y + w.z * a3.z + w.w * a3.w;
            }
            float cwv = sCW2[c];
            float t0 = silu_f(e0) * cwv;
            float t1 = silu_f(e1) * cwv;
            float t2 = silu_f(e2) * cwv;
            float t3 = silu_f(e3) * cwv;
            #pragma unroll
            for (int off = 32; off > 0; off >>= 1) {
                t0 += __shfl_xor(t0, off);
                t1 += __shfl_xor(t1, off);
                t2 += __shfl_xor(t2, off);
                t3 += __shfl_xor(t3, off);
            }
            if ((tid & 63) == 0) {
                int w4 = (tid >> 6) * 4;
                sRED[w4 + 0] = t0; sRED[w4 + 1] = t1;
                sRED[w4 + 2] = t2; sRED[w4 + 3] = t3;
            }
        }
        __syncthreads();                     // B4: RED ready

        #pragma unroll
        for (int jv = 0; jv < 4; ++jv) {
            float w = sRED[(2 * g) * 4 + jv] + sRED[(2 * g + 1) * 4 + jv] + cb2v;
            w *= mask[jv];
            ca0 += w * dx[jv];
            ca1 += w * dy[jv];
            ca2 += w * dz[jv];
        }
        // no barrier needed here (next writes are fenced by B1/B2/B3)
    }

    // combine h across the two groups; h_out = h_in + sum_j msg
    if (g == 1) sHP[c] = hreg;
    __syncthreads();
    if (g == 0) {
        float hv = hreg + sHP[c];
        h_out[node * HD + c] = h_in[node * HD + c] + hv;
    }
    // coord update accumulation (all threads of a group hold identical ca*)
    if ((tid & 127) == 0) {
        sCA[g * 4 + 0] = ca0; sCA[g * 4 + 1] = ca1; sCA[g * 4 + 2] = ca2;
    }
    __syncthreads();
    if (tid < 3) out[node * 3 + tid] += sCA[tid] + sCA[4 + tid];
}

extern "C" void kernel_launch(void* const* d_in, const int* in_sizes, int n_in,
                              void* d_out, int out_size, void* d_ws, size_t ws_size,
                              hipStream_t stream) {
    const float* x   = (const float*)d_in[0];
    const float* t   = (const float*)d_in[1];
    const float* tw1 = (const float*)d_in[2];
    const float* tb1 = (const float*)d_in[3];
    const float* tw2 = (const float*)d_in[4];
    const float* tb2 = (const float*)d_in[5];
    const float* mw1 = (const float*)d_in[6];
    const float* mb1 = (const float*)d_in[7];
    const float* mw2 = (const float*)d_in[8];
    const float* mb2 = (const float*)d_in[9];
    const float* cw1 = (const float*)d_in[10];
    const float* cb1 = (const float*)d_in[11];
    const float* cw2 = (const float*)d_in[12];
    const float* cb2 = (const float*)d_in[13];
    float* out = (float*)d_out;
    float* ws = (float*)d_ws;

    float* t_emb = ws;                       // 512
    float* h0 = ws + 512;                    // 262144
    float* h1 = h0 + 262144;                 // 262144
    float* Abuf = h1 + 262144;               // 262144
    float* Bbuf = Abuf + 262144;             // 262144

    hipMemsetAsync(d_out, 0, (size_t)out_size * sizeof(float), stream);
    k_time<<<BBATCH, 128, 0, stream>>>(t, tw1, tb1, tw2, tb2, t_emb);
    k_bcast<<<(BBATCH * NN * HD) / 256, 256, 0, stream>>>(t_emb, h0);

    float* hc = h0;
    float* hn = h1;
    const size_t shmem = (size_t)(128 * 132 * 2 + 128 * 17 + 128 * 3 + 8 * 128 * 2 +
                                  128 + 16 + 128 + 8) * sizeof(float);
    for (int l = 0; l < 4; ++l) {
        k_proj<<<BBATCH * NN, 128, 0, stream>>>(hc, mw1 + (size_t)l * 272 * 128,
                                                mb1 + l * 128, Abuf, Bbuf);
        k_edge<<<BBATCH * NN, 256, shmem, stream>>>(
            x, hc, hn, Abuf, Bbuf,
            mw1 + (size_t)l * 272 * 128 + 256 * 128,
            mw2 + (size_t)l * 128 * 128, mb2 + l * 128,
            cw1 + (size_t)l * 128 * 128, cb1 + l * 128,
            cw2 + l * 128, cb2 + l, out);
        float* tmp = hc; hc = hn; hn = tmp;
    }
}

// Round 2
// 1522.969 us; speedup vs baseline: 11.2423x; 11.2423x over previous
//
#include <hip/hip_runtime.h>
#include <hip/hip_bf16.h>
#include <math.h>

#define HD 128
#define NN 512
#define BBATCH 4

typedef __attribute__((ext_vector_type(8))) short bf16x8;
typedef __attribute__((ext_vector_type(4))) float f32x4;

#define MFMA16 __builtin_amdgcn_mfma_f32_16x16x32_bf16

__device__ __forceinline__ float silu_f(float v) { return v / (1.f + __expf(-v)); }

__device__ __forceinline__ short f2bf(float v) {
    union { __hip_bfloat16 h; short s; } u;
    u.h = __float2bfloat16(v);
    return u.s;
}
__device__ __forceinline__ float bf2f(short s) {
    union { __hip_bfloat16 h; short t; } u;
    u.t = s;
    return __bfloat162float(u.h);
}

// ---------------- time MLP: t -> t_emb (B,128) ----------------
__global__ void k_time(const float* __restrict__ t,
                       const float* __restrict__ w1, const float* __restrict__ b1,
                       const float* __restrict__ w2, const float* __restrict__ b2,
                       float* __restrict__ t_emb) {
    int b = blockIdx.x;
    int h = threadIdx.x;           // 0..127
    __shared__ float te[64];
    __shared__ float hid[128];
    float tv = t[b];
    if (h < 32) {
        const float cst = (float)(-2.302585092994046 * 4.0 / 31.0); // -ln(10000)/31
        float freq = __expf((float)h * cst);
        float ang = tv * freq;
        te[h]      = sinf(ang);
        te[h + 32] = cosf(ang);
    }
    __syncthreads();
    float acc = b1[h];
    #pragma unroll 8
    for (int k = 0; k < 64; ++k) acc += te[k] * w1[k * HD + h];
    hid[h] = silu_f(acc);
    __syncthreads();
    float acc2 = b2[h];
    #pragma unroll 8
    for (int k = 0; k < HD; ++k) acc2 += hid[k] * w2[k * HD + h];
    t_emb[b * HD + h] = acc2;
}

// ---------------- broadcast t_emb -> h (B,N,H) ----------------
__global__ void k_bcast(const float* __restrict__ t_emb, float* __restrict__ h) {
    int idx = blockIdx.x * 256 + threadIdx.x;   // B*N*H = 262144
    int hch = idx & 127;
    int b = idx >> 16;                           // N*H = 65536
    h[idx] = t_emb[b * HD + hch];
}

// ---------------- per-node projections A = h@W1_top + b1, Bp = h@W1_mid ----------------
__global__ void k_proj(const float* __restrict__ h,
                       const float* __restrict__ w1,   // (272,128) of this layer
                       const float* __restrict__ b1,
                       float* __restrict__ A, float* __restrict__ Bp) {
    int node = blockIdx.x;       // b*N+i, 2048 total
    int hc = threadIdx.x;        // 0..127
    __shared__ float hrow[HD];
    hrow[hc] = h[node * HD + hc];
    __syncthreads();
    float a = b1[hc];
    float bb = 0.f;
    #pragma unroll 8
    for (int k = 0; k < HD; ++k) {
        a  += hrow[k] * w1[k * HD + hc];
        bb += hrow[k] * w1[(HD + k) * HD + hc];
    }
    A[node * HD + hc]  = a;
    Bp[node * HD + hc] = bb;
}

// ---------------- MFMA edge kernel ----------------
// block = 256 threads = 4 waves; block <-> node i; 16 j's per iteration.
// Wave w owns output cols [w*32, w*32+32) as two 16-wide n-tiles.
// Weights held as hi/lo bf16 fragment pairs in registers (exact f32 split).
__global__ __launch_bounds__(256, 2)
void k_edge(const float* __restrict__ x, const float* __restrict__ h_in,
            float* __restrict__ h_out,
            const float* __restrict__ A, const float* __restrict__ Bp,
            const float* __restrict__ w1r,   // (16,128) rbf rows of msg_w1[l]
            const float* __restrict__ w2,    // (128,128)
            const float* __restrict__ b2,
            const float* __restrict__ cw1,   // (128,128)
            const float* __restrict__ cb1,
            const float* __restrict__ cw2,   // (128)
            const float* __restrict__ cb2,   // (1)
            float* __restrict__ out) {
    __shared__ short sRBF[16 * 32];     // A-frag layout [j][k], k>=16 zeroed once
    __shared__ short sMA[16 * 128];     // bf16, XOR-swizzled
    __shared__ short sMM[16 * 128];     // bf16, XOR-swizzled
    __shared__ float sMask[2][16];
    __shared__ float sDir[2][16][3];
    __shared__ float sRED[2][4][16];
    __shared__ float sHS[HD];
    __shared__ float sCA[16][3];

    const int tid = threadIdx.x;
    const int l  = tid & 63;
    const int w  = tid >> 6;            // wave 0..3
    const int lg = l >> 4;              // lane group 0..3
    const int ln = l & 15;
    const int nb = w * 32;
    const int n0 = nb + ln;
    const int n1 = n0 + 16;
    const int node = blockIdx.x;        // b*N + i
    const int b = node >> 9;
    const float* __restrict__ BpN = Bp + (size_t)b * NN * HD;

    // zero the RBF pad region (leftover LDS could be NaN-bf16; NaN*0=NaN)
    sRBF[tid] = 0; sRBF[tid + 256] = 0;

    // ---- per-lane constants ----
    const float ai0 = A[node * HD + n0];
    const float ai1 = A[node * HD + n1];
    const float bb20 = b2[n0], bb21 = b2[n1];
    const float cb10 = cb1[n0], cb11 = cb1[n1];
    const float cwv0 = cw2[n0], cwv1 = cw2[n1];
    const float cb2v = cb2[0];
    const float xi0 = x[node * 3 + 0], xi1 = x[node * 3 + 1], xi2 = x[node * 3 + 2];

    // ---- load weight fragments into registers (one-time) ----
    bf16x8 wR0, wR1;                    // rbf B-frags (single bf16; k>=16 zero)
    {
        int k0 = lg * 8;
        if (k0 < 16) {
            #pragma unroll
            for (int i = 0; i < 8; ++i) {
                wR0[i] = f2bf(w1r[(k0 + i) * HD + n0]);
                wR1[i] = f2bf(w1r[(k0 + i) * HD + n1]);
            }
        } else {
            #pragma unroll
            for (int i = 0; i < 8; ++i) { wR0[i] = 0; wR1[i] = 0; }
        }
    }
    bf16x8 wH[2][4], wL[2][4], cH[2][4], cL[2][4];
    #pragma unroll
    for (int nt = 0; nt < 2; ++nt) {
        int n = nb + nt * 16 + ln;
        #pragma unroll
        for (int ks = 0; ks < 4; ++ks) {
            int kb = ks * 32 + lg * 8;
            #pragma unroll
            for (int i = 0; i < 8; ++i) {
                float v = w2[(kb + i) * HD + n];
                short hi = f2bf(v);
                wH[nt][ks][i] = hi;
                wL[nt][ks][i] = f2bf(v - bf2f(hi));
                float u = cw1[(kb + i) * HD + n];
                short h2 = f2bf(u);
                cH[nt][ks][i] = h2;
                cL[nt][ks][i] = f2bf(u - bf2f(h2));
            }
        }
    }

    float hreg0 = 0.f, hreg1 = 0.f;
    float ca0 = 0.f, ca1 = 0.f, ca2 = 0.f;
    const float cstep = 10.f / 15.f;
    __syncthreads();

    for (int it = 0; it < 32; ++it) {
        const int jb = it * 16;
        const int p = it & 1;
        // ---- ph1: dist / rbf / mask / dir for 16 j's (thread = (j, r)) ----
        {
            int jj = tid >> 4, r = tid & 15;
            int j = jb + jj;
            float d0 = x[(b * NN + j) * 3 + 0] - xi0;
            float d1 = x[(b * NN + j) * 3 + 1] - xi1;
            float d2 = x[(b * NN + j) * 3 + 2] - xi2;
            float d = sqrtf(d0 * d0 + d1 * d1 + d2 * d2);
            float dd = d - (float)r * cstep;
            sRBF[jj * 32 + r] = f2bf(__expf(-dd * dd * 1.28f));
            float inv = 1.f / (d + 1e-8f);
            if (r == 0)      sDir[p][jj][0] = d0 * inv;
            else if (r == 1) sDir[p][jj][1] = d1 * inv;
            else if (r == 2) sDir[p][jj][2] = d2 * inv;
            else if (r == 3) sMask[p][jj] = (d < 10.f && d > 0.f) ? 1.f : 0.f;
        }
        __syncthreads();                 // B0

        // ---- ph2: preact = rbf@W1r + A_i + Bp_j ; silu -> sMA (bf16) ----
        {
            float bp0[4], bp1[4];
            #pragma unroll
            for (int reg = 0; reg < 4; ++reg) {
                int j = jb + lg * 4 + reg;
                bp0[reg] = BpN[j * HD + n0];
                bp1[reg] = BpN[j * HD + n1];
            }
            bf16x8 aR = *(const bf16x8*)&sRBF[ln * 32 + lg * 8];
            f32x4 z = {0.f, 0.f, 0.f, 0.f};
            f32x4 acc0 = MFMA16(aR, wR0, z, 0, 0, 0);
            f32x4 acc1 = MFMA16(aR, wR1, z, 0, 0, 0);
            #pragma unroll
            for (int reg = 0; reg < 4; ++reg) {
                int m = lg * 4 + reg;
                short v0 = f2bf(silu_f(acc0[reg] + ai0 + bp0[reg]));
                short v1 = f2bf(silu_f(acc1[reg] + ai1 + bp1[reg]));
                *(short*)((char*)sMA + ((((m << 8) + (n0 << 1))) ^ ((m & 7) << 4))) = v0;
                *(short*)((char*)sMA + ((((m << 8) + (n1 << 1))) ^ ((m & 7) << 4))) = v1;
            }
        }
        __syncthreads();                 // B1

        // ---- ph3: MSG = MA @ (W2h+W2l) + b2 ; mask ; h-sum ; -> sMM ----
        {
            bf16x8 aM[4];
            #pragma unroll
            for (int ks = 0; ks < 4; ++ks) {
                int off = ((ln << 8) + ((ks * 32 + lg * 8) << 1)) ^ ((ln & 7) << 4);
                aM[ks] = *(const bf16x8*)((char*)sMA + off);
            }
            f32x4 acc0 = {bb20, bb20, bb20, bb20};
            f32x4 acc1 = {bb21, bb21, bb21, bb21};
            #pragma unroll
            for (int ks = 0; ks < 4; ++ks) acc0 = MFMA16(aM[ks], wL[0][ks], acc0, 0, 0, 0);
            #pragma unroll
            for (int ks = 0; ks < 4; ++ks) acc0 = MFMA16(aM[ks], wH[0][ks], acc0, 0, 0, 0);
            #pragma unroll
            for (int ks = 0; ks < 4; ++ks) acc1 = MFMA16(aM[ks], wL[1][ks], acc1, 0, 0, 0);
            #pragma unroll
            for (int ks = 0; ks < 4; ++ks) acc1 = MFMA16(aM[ks], wH[1][ks], acc1, 0, 0, 0);
            #pragma unroll
            for (int reg = 0; reg < 4; ++reg) {
                int m = lg * 4 + reg;
                float msk = sMask[p][m];
                float g0 = acc0[reg] * msk;
                float g1 = acc1[reg] * msk;
                hreg0 += g0; hreg1 += g1;
                *(short*)((char*)sMM + ((((m << 8) + (n0 << 1))) ^ ((m & 7) << 4))) = f2bf(g0);
                *(short*)((char*)sMM + ((((m << 8) + (n1 << 1))) ^ ((m & 7) << 4))) = f2bf(g1);
            }
        }
        __syncthreads();                 // B2

        // ---- ph4: CH = silu(MM @ (C1h+C1l) + cb1) ; dot cw2 ; row-reduce ----
        {
            bf16x8 aM[4];
            #pragma unroll
            for (int ks = 0; ks < 4; ++ks) {
                int off = ((ln << 8) + ((ks * 32 + lg * 8) << 1)) ^ ((ln & 7) << 4);
                aM[ks] = *(const bf16x8*)((char*)sMM + off);
            }
            f32x4 acc0 = {cb10, cb10, cb10, cb10};
            f32x4 acc1 = {cb11, cb11, cb11, cb11};
            #pragma unroll
            for (int ks = 0; ks < 4; ++ks) acc0 = MFMA16(aM[ks], cL[0][ks], acc0, 0, 0, 0);
            #pragma unroll
            for (int ks = 0; ks < 4; ++ks) acc0 = MFMA16(aM[ks], cH[0][ks], acc0, 0, 0, 0);
            #pragma unroll
            for (int ks = 0; ks < 4; ++ks) acc1 = MFMA16(aM[ks], cL[1][ks], acc1, 0, 0, 0);
            #pragma unroll
            for (int ks = 0; ks < 4; ++ks) acc1 = MFMA16(aM[ks], cH[1][ks], acc1, 0, 0, 0);
            #pragma unroll
            for (int reg = 0; reg < 4; ++reg) {
                float v = silu_f(acc0[reg]) * cwv0 + silu_f(acc1[reg]) * cwv1;
                v += __shfl_xor(v, 1);
                v += __shfl_xor(v, 2);
                v += __shfl_xor(v, 4);
                v += __shfl_xor(v, 8);
                if (ln == 0) sRED[p][w][lg * 4 + reg] = v;
            }
        }
        __syncthreads();                 // B3

        // ---- ph5: edge weights -> coord accumulation (threads 0..15) ----
        if (tid < 16) {
            float wsum = sRED[p][0][tid] + sRED[p][1][tid] +
                         sRED[p][2][tid] + sRED[p][3][tid] + cb2v;
            wsum *= sMask[p][tid];
            ca0 += wsum * sDir[p][tid][0];
            ca1 += wsum * sDir[p][tid][1];
            ca2 += wsum * sDir[p][tid][2];
        }
        // no barrier: next ph1 writes the p^1 buffers
    }

    // ---- epilogue: h_out and coord updates ----
    float t0 = hreg0; t0 += __shfl_xor(t0, 16); t0 += __shfl_xor(t0, 32);
    float t1 = hreg1; t1 += __shfl_xor(t1, 16); t1 += __shfl_xor(t1, 32);
    if (l < 16) { sHS[n0] = t0; sHS[n1] = t1; }
    if (tid < 16) { sCA[tid][0] = ca0; sCA[tid][1] = ca1; sCA[tid][2] = ca2; }
    __syncthreads();
    if (tid < HD) h_out[node * HD + tid] = h_in[node * HD + tid] + sHS[tid];
    if (tid < 3) {
        float s = 0.f;
        #pragma unroll
        for (int jj = 0; jj < 16; ++jj) s += sCA[jj][tid];
        out[node * 3 + tid] += s;
    }
}

extern "C" void kernel_launch(void* const* d_in, const int* in_sizes, int n_in,
                              void* d_out, int out_size, void* d_ws, size_t ws_size,
                              hipStream_t stream) {
    const float* x   = (const float*)d_in[0];
    const float* t   = (const float*)d_in[1];
    const float* tw1 = (const float*)d_in[2];
    const float* tb1 = (const float*)d_in[3];
    const float* tw2 = (const float*)d_in[4];
    const float* tb2 = (const float*)d_in[5];
    const float* mw1 = (const float*)d_in[6];
    const float* mb1 = (const float*)d_in[7];
    const float* mw2 = (const float*)d_in[8];
    const float* mb2 = (const float*)d_in[9];
    const float* cw1 = (const float*)d_in[10];
    const float* cb1 = (const float*)d_in[11];
    const float* cw2 = (const float*)d_in[12];
    const float* cb2 = (const float*)d_in[13];
    float* out = (float*)d_out;
    float* ws = (float*)d_ws;

    float* t_emb = ws;                       // 512
    float* h0 = ws + 512;                    // 262144
    float* h1 = h0 + 262144;                 // 262144
    float* Abuf = h1 + 262144;               // 262144
    float* Bbuf = Abuf + 262144;             // 262144

    hipMemsetAsync(d_out, 0, (size_t)out_size * sizeof(float), stream);
    k_time<<<BBATCH, 128, 0, stream>>>(t, tw1, tb1, tw2, tb2, t_emb);
    k_bcast<<<(BBATCH * NN * HD) / 256, 256, 0, stream>>>(t_emb, h0);

    float* hc = h0;
    float* hn = h1;
    for (int l = 0; l < 4; ++l) {
        k_proj<<<BBATCH * NN, 128, 0, stream>>>(hc, mw1 + (size_t)l * 272 * 128,
                                                mb1 + l * 128, Abuf, Bbuf);
        k_edge<<<BBATCH * NN, 256, 0, stream>>>(
            x, hc, hn, Abuf, Bbuf,
            mw1 + (size_t)l * 272 * 128 + 256 * 128,
            mw2 + (size_t)l * 128 * 128, mb2 + l * 128,
            cw1 + (size_t)l * 128 * 128, cb1 + l * 128,
            cw2 + l * 128, cb2 + l, out);
        float* tmp = hc; hc = hn; hn = tmp;
    }
}

// Round 3
// 1127.871 us; speedup vs baseline: 15.1805x; 1.3503x over previous
//
#include <hip/hip_runtime.h>
#include <hip/hip_bf16.h>
#include <math.h>

#define HD 128
#define NN 512
#define BBATCH 4
#define JT 32

typedef __attribute__((ext_vector_type(8))) short bf16x8;
typedef __attribute__((ext_vector_type(4))) float f32x4;
typedef unsigned int uint;
typedef unsigned short ushort;

#define MFMA16 __builtin_amdgcn_mfma_f32_16x16x32_bf16

__device__ __forceinline__ float silu_f(float v) { return v / (1.f + __expf(-v)); }

__device__ __forceinline__ short f2bf(float v) {
    union { __hip_bfloat16 h; short s; } u;
    u.h = __float2bfloat16(v);
    return u.s;
}

// ---------------- time MLP: t -> t_emb (B,128) ----------------
__global__ void k_time(const float* __restrict__ t,
                       const float* __restrict__ w1, const float* __restrict__ b1,
                       const float* __restrict__ w2, const float* __restrict__ b2,
                       float* __restrict__ t_emb) {
    int b = blockIdx.x;
    int h = threadIdx.x;           // 0..127
    __shared__ float te[64];
    __shared__ float hid[128];
    float tv = t[b];
    if (h < 32) {
        const float cst = (float)(-2.302585092994046 * 4.0 / 31.0); // -ln(10000)/31
        float freq = __expf((float)h * cst);
        float ang = tv * freq;
        te[h]      = sinf(ang);
        te[h + 32] = cosf(ang);
    }
    __syncthreads();
    float acc = b1[h];
    #pragma unroll 8
    for (int k = 0; k < 64; ++k) acc += te[k] * w1[k * HD + h];
    hid[h] = silu_f(acc);
    __syncthreads();
    float acc2 = b2[h];
    #pragma unroll 8
    for (int k = 0; k < HD; ++k) acc2 += hid[k] * w2[k * HD + h];
    t_emb[b * HD + h] = acc2;
}

// ---------------- broadcast t_emb -> h (B,N,H) f32 + bf16 ----------------
__global__ void k_bcast(const float* __restrict__ t_emb, float* __restrict__ h,
                        ushort* __restrict__ hb) {
    int idx = blockIdx.x * 256 + threadIdx.x;   // B*N*H = 262144
    int hch = idx & 127;
    int b = idx >> 16;                           // N*H = 65536
    float v = t_emb[b * HD + hch];
    h[idx] = v;
    hb[idx] = (ushort)f2bf(v);
}

// ---------------- per-node projection A = h@W1_top + b1 ----------------
__global__ void k_proj(const float* __restrict__ h,
                       const float* __restrict__ w1,   // (272,128) of this layer
                       const float* __restrict__ b1,
                       float* __restrict__ A) {
    int node = blockIdx.x;       // b*N+i, 2048 total
    int hc = threadIdx.x;        // 0..127
    __shared__ float hrow[HD];
    hrow[hc] = h[node * HD + hc];
    __syncthreads();
    float a = b1[hc];
    #pragma unroll 8
    for (int k = 0; k < HD; ++k) a += hrow[k] * w1[k * HD + hc];
    A[node * HD + hc] = a;
}

// ---------------- MFMA edge kernel ----------------
// block = 256 = 4 waves; block <-> node i; 32 j's per iteration (16 iters).
// Wave w owns output cols [w*32, w*32+32) as two 16-wide n-tiles.
// Edge GEMM A-operand = [h_j(128) | rbf(16) | 1 | 0...] (K=160) staged in LDS,
// so pre-act = h_j@W1mid + rbf@W1r + A_i needs no per-edge global loads.
__global__ __launch_bounds__(256, 2)
void k_edge(const float* __restrict__ x,
            const float* __restrict__ h_in, const ushort* __restrict__ hb_in,
            float* __restrict__ h_out, ushort* __restrict__ hb_out,
            const float* __restrict__ A,
            const float* __restrict__ w1,    // (272,128) layer base
            const float* __restrict__ w2,    // (128,128)
            const float* __restrict__ b2,
            const float* __restrict__ cw1,   // (128,128)
            const float* __restrict__ cb1,
            const float* __restrict__ cw2,   // (128)
            const float* __restrict__ cb2,   // (1)
            float* __restrict__ out) {
    // LDS: A-tile double-buffered [32 rows][512B pitch], XOR-swizzled 16B chunks
    __shared__ uint4 sAq[2][JT * 32];            // 2 x 16 KB
    __shared__ uint4 sMAq[JT * 16];              // 8 KB  [32][256B]
    __shared__ uint4 sMMq[JT * 16];              // 8 KB
    __shared__ __align__(16) float sPart[JT * 68];  // [32][272B]
    __shared__ float sDir[2][JT][3];
    __shared__ float sMask[2][JT];
    __shared__ float sHS[HD];
    __shared__ float sCA[JT][3];

    const int tid = threadIdx.x;
    const int l  = tid & 63;
    const int w  = tid >> 6;            // wave 0..3
    const int lg = l >> 4;              // lane k-group 0..3
    const int ln = l & 15;
    const int nb = w * 32;
    const int n0 = nb + ln;
    const int n1 = n0 + 16;
    const int node = blockIdx.x;        // b*N + i
    const int b = node >> 9;
    const float* __restrict__ xb = x + (size_t)b * NN * 3;
    const ushort* __restrict__ hbN = hb_in + (size_t)b * NN * HD;

    const float* w1m = w1 + 128 * HD;   // h_j rows
    const float* w1r = w1 + 256 * HD;   // rbf rows

    // ---- per-lane constants ----
    const float bb20 = b2[n0], bb21 = b2[n1];
    const float cb10 = cb1[n0], cb11 = cb1[n1];
    const float cwv0 = cw2[n0], cwv1 = cw2[n1];
    const float cb2v = cb2[0];
    const float xi0 = x[node * 3 + 0], xi1 = x[node * 3 + 1], xi2 = x[node * 3 + 2];
    const float cstep = 10.f / 15.f;
    const float rbfk = 1.28f;

    // ---- weight fragments (single bf16) ----
    bf16x8 wM[2][4], w2f[2][4], c1f[2][4], wR[2];
    #pragma unroll
    for (int nt = 0; nt < 2; ++nt) {
        int n = nb + nt * 16 + ln;
        #pragma unroll
        for (int ks = 0; ks < 4; ++ks) {
            #pragma unroll
            for (int i = 0; i < 8; ++i) {
                int k = ks * 32 + lg * 8 + i;
                wM[nt][ks][i]  = f2bf(w1m[k * HD + n]);
                w2f[nt][ks][i] = f2bf(w2[k * HD + n]);
                c1f[nt][ks][i] = f2bf(cw1[k * HD + n]);
            }
        }
        #pragma unroll
        for (int i = 0; i < 8; ++i) {
            int kr = lg * 8 + i;
            float v = (kr < 16) ? w1r[kr * HD + n]
                    : (kr == 16 ? A[node * HD + n] : 0.f);
            wR[nt][i] = f2bf(v);
        }
    }

    // ---- init constant A-tile regions (k=144 ones, k=145..159 zeros), both buffers
    if (tid < 64) {
        char* base = (char*)sAq[tid >> 5] + (tid & 31) * 512;
        int sw = ((tid & 7) << 4);
        *(uint*)(base + (288 ^ sw) + 0)  = 0x00003F80u;  // k144=1.0bf, k145=0
        *(uint*)(base + (288 ^ sw) + 4)  = 0u;
        *(uint*)(base + (288 ^ sw) + 8)  = 0u;
        *(uint*)(base + (288 ^ sw) + 12) = 0u;
        uint4 z4 = {0u, 0u, 0u, 0u};
        *(uint4*)(base + (304 ^ sw)) = z4;               // k152..159
    }

    const int hr = tid >> 4, hseg = tid & 15;
    const int jj = tid >> 3, rp = tid & 7;

    // ---- prologue: stage tile 0 ----
    {
        char* bufc = (char*)sAq[0];
        const ushort* src = hbN + (size_t)hr * HD + hseg * 8;
        uint4 hv0 = *(const uint4*)src;
        uint4 hv1 = *(const uint4*)(src + 16 * HD);
        // geometry tile 0
        const float* xj = xb + jj * 3;
        float d0 = xj[0] - xi0, d1 = xj[1] - xi1, d2 = xj[2] - xi2;
        float d = sqrtf(d0 * d0 + d1 * d1 + d2 * d2);
        float c0 = (float)(rp * 2) * cstep;
        float e0 = __expf(-(d - c0) * (d - c0) * rbfk);
        float e1 = __expf(-(d - c0 - cstep) * (d - c0 - cstep) * rbfk);
        uint pk = (uint)(ushort)f2bf(e0) | ((uint)(ushort)f2bf(e1) << 16);
        *(uint*)(bufc + jj * 512 + ((256 + (rp & 4) * 4) ^ ((jj & 7) << 4)) + (rp & 3) * 4) = pk;
        if (rp == 0) {
            float inv = 1.f / (d + 1e-8f);
            sDir[0][jj][0] = d0 * inv; sDir[0][jj][1] = d1 * inv; sDir[0][jj][2] = d2 * inv;
            sMask[0][jj] = (d < 10.f && d > 0.f) ? 1.f : 0.f;
        }
        int off = (hseg * 16) ^ ((hr & 7) << 4);
        *(uint4*)(bufc + hr * 512 + off) = hv0;
        *(uint4*)(bufc + (hr + 16) * 512 + off) = hv1;
    }
    float hreg0 = 0.f, hreg1 = 0.f;
    float ca0 = 0.f, ca1 = 0.f, ca2 = 0.f;
    __syncthreads();

    const int swA = (ln & 7) << 4;
    const int colb0 = nb * 2 + (ln & 8) * 2 + (ln & 7) * 2;          // byte of col n0 in row
    const int colb1 = (nb + 16) * 2 + (ln & 8) * 2 + (ln & 7) * 2;   // byte of col n1

    for (int it = 0; it <= 16; ++it) {
        // ---- ph5 (software-pipelined): edge weights of tile it-1 -> coord accum
        if (it > 0) {
            const int pm = (it - 1) & 1;
            const char* pp = (const char*)sPart + jj * 272;
            f32x4 pa = *(const f32x4*)(pp + ((jj & 7) << 4 ^ (rp * 32)));
            f32x4 pb = *(const f32x4*)(pp + ((jj & 7) << 4 ^ (rp * 32 + 16)));
            float s = pa[0] + pa[1] + pa[2] + pa[3] + pb[0] + pb[1] + pb[2] + pb[3];
            s += __shfl_xor(s, 1); s += __shfl_xor(s, 2); s += __shfl_xor(s, 4);
            if (rp == 0) {
                float wv = (s + cb2v) * sMask[pm][jj];
                ca0 += wv * sDir[pm][jj][0];
                ca1 += wv * sDir[pm][jj][1];
                ca2 += wv * sDir[pm][jj][2];
            }
        }
        if (it == 16) break;
        const int p = it & 1;

        // ---- stage + geometry for tile it+1 (issue loads early, write after ph2)
        uint4 hv0, hv1;
        if (it < 15) {
            const ushort* src = hbN + (size_t)((it + 1) * JT + hr) * HD + hseg * 8;
            hv0 = *(const uint4*)src;
            hv1 = *(const uint4*)(src + 16 * HD);
            char* bufn = (char*)sAq[p ^ 1];
            int j = (it + 1) * JT + jj;
            const float* xj = xb + j * 3;
            float d0 = xj[0] - xi0, d1 = xj[1] - xi1, d2 = xj[2] - xi2;
            float d = sqrtf(d0 * d0 + d1 * d1 + d2 * d2);
            float c0 = (float)(rp * 2) * cstep;
            float e0 = __expf(-(d - c0) * (d - c0) * rbfk);
            float e1 = __expf(-(d - c0 - cstep) * (d - c0 - cstep) * rbfk);
            uint pk = (uint)(ushort)f2bf(e0) | ((uint)(ushort)f2bf(e1) << 16);
            *(uint*)(bufn + jj * 512 + ((256 + (rp & 4) * 4) ^ ((jj & 7) << 4)) + (rp & 3) * 4) = pk;
            if (rp == 0) {
                float inv = 1.f / (d + 1e-8f);
                sDir[p ^ 1][jj][0] = d0 * inv; sDir[p ^ 1][jj][1] = d1 * inv; sDir[p ^ 1][jj][2] = d2 * inv;
                sMask[p ^ 1][jj] = (d < 10.f && d > 0.f) ? 1.f : 0.f;
            }
        }

        // ---- ph2: pre-act GEMM  [h_j|rbf|1] @ [W1mid;W1r;A_i]  -> silu -> sMA
        {
            const char* bufc = (const char*)sAq[p];
            f32x4 zz = {0.f, 0.f, 0.f, 0.f};
            f32x4 pacc[2][2];
            #pragma unroll
            for (int mt = 0; mt < 2; ++mt) {
                pacc[mt][0] = zz; pacc[mt][1] = zz;
                const char* rowp = bufc + (ln + mt * 16) * 512;
                bf16x8 af[5];
                #pragma unroll
                for (int ks = 0; ks < 5; ++ks)
                    af[ks] = *(const bf16x8*)(rowp + ((ks * 64 + lg * 16) ^ swA));
                #pragma unroll
                for (int ks = 0; ks < 4; ++ks) {
                    pacc[mt][0] = MFMA16(af[ks], wM[0][ks], pacc[mt][0], 0, 0, 0);
                    pacc[mt][1] = MFMA16(af[ks], wM[1][ks], pacc[mt][1], 0, 0, 0);
                }
                pacc[mt][0] = MFMA16(af[4], wR[0], pacc[mt][0], 0, 0, 0);
                pacc[mt][1] = MFMA16(af[4], wR[1], pacc[mt][1], 0, 0, 0);
            }
            #pragma unroll
            for (int mt = 0; mt < 2; ++mt)
                #pragma unroll
                for (int reg = 0; reg < 4; ++reg) {
                    int j = mt * 16 + lg * 4 + reg;
                    int sw = (j & 7) << 4;
                    *(short*)((char*)sMAq + j * 256 + (colb0 ^ sw)) = f2bf(silu_f(pacc[mt][0][reg]));
                    *(short*)((char*)sMAq + j * 256 + (colb1 ^ sw)) = f2bf(silu_f(pacc[mt][1][reg]));
                }
        }
        // ---- write staged h for tile it+1 (loads issued before ph2)
        if (it < 15) {
            char* bufn = (char*)sAq[p ^ 1];
            int off = (hseg * 16) ^ ((hr & 7) << 4);
            *(uint4*)(bufn + hr * 512 + off) = hv0;
            *(uint4*)(bufn + (hr + 16) * 512 + off) = hv1;
        }
        __syncthreads();                 // B1: sMA + next A-tile staged

        // ---- ph3: MSG = MA @ W2 + b2 ; mask ; h-sum ; -> sMM
        {
            f32x4 macc[2][2];
            f32x4 i0 = {bb20, bb20, bb20, bb20};
            f32x4 i1 = {bb21, bb21, bb21, bb21};
            #pragma unroll
            for (int mt = 0; mt < 2; ++mt) {
                macc[mt][0] = i0; macc[mt][1] = i1;
                const char* rowp = (const char*)sMAq + (ln + mt * 16) * 256;
                bf16x8 am[4];
                #pragma unroll
                for (int ks = 0; ks < 4; ++ks)
                    am[ks] = *(const bf16x8*)(rowp + ((ks * 64 + lg * 16) ^ swA));
                #pragma unroll
                for (int ks = 0; ks < 4; ++ks) {
                    macc[mt][0] = MFMA16(am[ks], w2f[0][ks], macc[mt][0], 0, 0, 0);
                    macc[mt][1] = MFMA16(am[ks], w2f[1][ks], macc[mt][1], 0, 0, 0);
                }
            }
            #pragma unroll
            for (int mt = 0; mt < 2; ++mt)
                #pragma unroll
                for (int reg = 0; reg < 4; ++reg) {
                    int j = mt * 16 + lg * 4 + reg;
                    float msk = sMask[p][j];
                    float g0 = macc[mt][0][reg] * msk;
                    float g1 = macc[mt][1][reg] * msk;
                    hreg0 += g0; hreg1 += g1;
                    int sw = (j & 7) << 4;
                    *(short*)((char*)sMMq + j * 256 + (colb0 ^ sw)) = f2bf(g0);
                    *(short*)((char*)sMMq + j * 256 + (colb1 ^ sw)) = f2bf(g1);
                }
        }
        __syncthreads();                 // B2: sMM ready

        // ---- ph4: CH = silu(MM @ cw1 + cb1); partial dot with cw2 -> sPart
        {
            f32x4 cacc[2][2];
            f32x4 i0 = {cb10, cb10, cb10, cb10};
            f32x4 i1 = {cb11, cb11, cb11, cb11};
            #pragma unroll
            for (int mt = 0; mt < 2; ++mt) {
                cacc[mt][0] = i0; cacc[mt][1] = i1;
                const char* rowp = (const char*)sMMq + (ln + mt * 16) * 256;
                bf16x8 am[4];
                #pragma unroll
                for (int ks = 0; ks < 4; ++ks)
                    am[ks] = *(const bf16x8*)(rowp + ((ks * 64 + lg * 16) ^ swA));
                #pragma unroll
                for (int ks = 0; ks < 4; ++ks) {
                    cacc[mt][0] = MFMA16(am[ks], c1f[0][ks], cacc[mt][0], 0, 0, 0);
                    cacc[mt][1] = MFMA16(am[ks], c1f[1][ks], cacc[mt][1], 0, 0, 0);
                }
            }
            #pragma unroll
            for (int mt = 0; mt < 2; ++mt)
                #pragma unroll
                for (int reg = 0; reg < 4; ++reg) {
                    int j = mt * 16 + lg * 4 + reg;
                    float v = silu_f(cacc[mt][0][reg]) * cwv0 + silu_f(cacc[mt][1][reg]) * cwv1;
                    *(float*)((char*)sPart + j * 272 + (((w * 16 + ln) * 4) ^ ((j & 7) << 4))) = v;
                }
        }
        __syncthreads();                 // B3: sPart ready
    }

    // ---- epilogue ----
    float t0 = hreg0 + __shfl_xor(hreg0, 16); t0 += __shfl_xor(t0, 32);
    float t1 = hreg1 + __shfl_xor(hreg1, 16); t1 += __shfl_xor(t1, 32);
    if (lg == 0) { sHS[n0] = t0; sHS[n1] = t1; }
    if (rp == 0) { sCA[jj][0] = ca0; sCA[jj][1] = ca1; sCA[jj][2] = ca2; }
    __syncthreads();
    if (tid < HD) {
        float hv = h_in[node * HD + tid] + sHS[tid];
        h_out[node * HD + tid] = hv;
        hb_out[node * HD + tid] = (ushort)f2bf(hv);
    }
    if (tid < 3) {
        float s = 0.f;
        #pragma unroll
        for (int q = 0; q < JT; ++q) s += sCA[q][tid];
        out[node * 3 + tid] += s;
    }
}

extern "C" void kernel_launch(void* const* d_in, const int* in_sizes, int n_in,
                              void* d_out, int out_size, void* d_ws, size_t ws_size,
                              hipStream_t stream) {
    const float* x   = (const float*)d_in[0];
    const float* t   = (const float*)d_in[1];
    const float* tw1 = (const float*)d_in[2];
    const float* tb1 = (const float*)d_in[3];
    const float* tw2 = (const float*)d_in[4];
    const float* tb2 = (const float*)d_in[5];
    const float* mw1 = (const float*)d_in[6];
    const float* mb1 = (const float*)d_in[7];
    const float* mw2 = (const float*)d_in[8];
    const float* mb2 = (const float*)d_in[9];
    const float* cw1 = (const float*)d_in[10];
    const float* cb1 = (const float*)d_in[11];
    const float* cw2 = (const float*)d_in[12];
    const float* cb2 = (const float*)d_in[13];
    float* out = (float*)d_out;
    float* ws = (float*)d_ws;

    float* t_emb = ws;                          // 512
    float* h0 = ws + 512;                       // 262144
    float* h1 = h0 + 262144;                    // 262144
    float* Abuf = h1 + 262144;                  // 262144
    ushort* hb0 = (ushort*)(Abuf + 262144);     // 262144 ushort
    ushort* hb1 = hb0 + 262144;                 // 262144 ushort

    hipMemsetAsync(d_out, 0, (size_t)out_size * sizeof(float), stream);
    k_time<<<BBATCH, 128, 0, stream>>>(t, tw1, tb1, tw2, tb2, t_emb);
    k_bcast<<<(BBATCH * NN * HD) / 256, 256, 0, stream>>>(t_emb, h0, hb0);

    float* hc = h0;  ushort* hbc = hb0;
    float* hn = h1;  ushort* hbn = hb1;
    for (int l = 0; l < 4; ++l) {
        k_proj<<<BBATCH * NN, 128, 0, stream>>>(hc, mw1 + (size_t)l * 272 * 128,
                                                mb1 + l * 128, Abuf);
        k_edge<<<BBATCH * NN, 256, 0, stream>>>(
            x, hc, hbc, hn, hbn, Abuf,
            mw1 + (size_t)l * 272 * 128,
            mw2 + (size_t)l * 128 * 128, mb2 + l * 128,
            cw1 + (size_t)l * 128 * 128, cb1 + l * 128,
            cw2 + l * 128, cb2 + l, out);
        float* tf = hc; hc = hn; hn = tf;
        ushort* tb = hbc; hbc = hbn; hbn = tb;
    }
}